// Round 1
// baseline (540.244 us; speedup 1.0000x reference)
//
#include <hip/hip_runtime.h>

constexpr int B = 8, S = 2048, D = 256;
constexpr int TQ = 16;              // query rows per block (halved: 2 blocks/CU)
constexpr float SCALE = 0.0625f;    // 1/sqrt(256)
constexpr int PSTRIDE = 2056;       // 2048 + 8 bf16 pad -> 2-way bank aliasing (free)

typedef __attribute__((ext_vector_type(8))) short bf16x8;  // 8 bf16 in 4 VGPRs
typedef __attribute__((ext_vector_type(4))) float f32x4;

__device__ __forceinline__ short f2bf(float f) {
    union { float f; unsigned u; } c; c.f = f;
    unsigned u = c.u + 0x7fffu + ((c.u >> 16) & 1u);   // RNE
    return (short)(u >> 16);
}

// ---- pre-pass 1: fp32 -> bf16 elementwise (q, k) ----
__global__ void conv_bf16(const float* __restrict__ in, short* __restrict__ out, int n4) {
    int i = blockIdx.x * blockDim.x + threadIdx.x;
    if (i < n4) {
        float4 v = ((const float4*)in)[i];
        short4 o; o.x = f2bf(v.x); o.y = f2bf(v.y); o.z = f2bf(v.z); o.w = f2bf(v.w);
        ((short4*)out)[i] = o;
    }
}

// ---- pre-pass 2: V [B][S][D] fp32 -> V^T [B][D][S] bf16 ----
__global__ void transpose_v(const float* __restrict__ v, short* __restrict__ vt) {
    const int b = blockIdx.z;
    const int d0 = blockIdx.x * 64, k0 = blockIdx.y * 64;
    const int t = threadIdx.x;
    const int tr = t >> 4, tc = t & 15;
    __shared__ float tile[64][65];
    const float* vb = v + (size_t)b * S * D;
    #pragma unroll
    for (int r = 0; r < 4; ++r) {
        int key = r * 16 + tr;
        float4 x = *(const float4*)(vb + (size_t)(k0 + key) * D + d0 + tc * 4);
        tile[key][tc * 4 + 0] = x.x; tile[key][tc * 4 + 1] = x.y;
        tile[key][tc * 4 + 2] = x.z; tile[key][tc * 4 + 3] = x.w;
    }
    __syncthreads();
    short* vtb = vt + (size_t)b * D * S;
    #pragma unroll
    for (int r = 0; r < 4; ++r) {
        int d = r * 16 + tr;
        short4 o;
        o.x = f2bf(tile[tc * 4 + 0][d]); o.y = f2bf(tile[tc * 4 + 1][d]);
        o.z = f2bf(tile[tc * 4 + 2][d]); o.w = f2bf(tile[tc * 4 + 3][d]);
        *(short4*)(vtb + (size_t)(d0 + d) * S + k0 + tc * 4) = o;
    }
}

// ---- main fused kernel: 512 threads (8 waves), 1 block = 16 q-rows x 1 batch ----
// LDS: p_lds 16*2056*2 = 64.25 KB + red 0.5 KB -> 66.3 KB -> 2 blocks/CU
// __launch_bounds__(512,4): 4 waves/EU -> <=128 combined VGPR+AGPR -> 16 waves/CU
__global__ __launch_bounds__(512, 4) void attn_mfma(
    const short* __restrict__ qb, const short* __restrict__ kb,
    const short* __restrict__ vtb, const int* __restrict__ maskg,
    float* __restrict__ outg, float* __restrict__ attng)
{
    const int b = blockIdx.y;
    const int i0 = blockIdx.x * TQ;
    const int tid = threadIdx.x;
    const int wave = tid >> 6, lane = tid & 63;
    const int quad = lane >> 4, l16 = lane & 15;

    __shared__ short p_lds[TQ][PSTRIDE];
    __shared__ float red[8][TQ];

    // ---------- phase A: scores = Q K^T (wave w owns keys [w*256, w*256+256)) ----------
    bf16x8 aq[8];
    const short* qbase = qb + ((size_t)b * S + i0) * D;
    #pragma unroll
    for (int ks = 0; ks < 8; ++ks)
        aq[ks] = *(const bf16x8*)(qbase + (size_t)l16 * D + ks * 32 + quad * 8);

    f32x4 acc[16];
    #pragma unroll
    for (int nt = 0; nt < 16; ++nt)
        acc[nt] = f32x4{0.f, 0.f, 0.f, 0.f};

    const short* kbase = kb + (size_t)b * S * D;
    #pragma unroll
    for (int nt = 0; nt < 16; ++nt) {
        const int n0 = wave * 256 + nt * 16;
        bf16x8 bk[8];
        #pragma unroll
        for (int ks = 0; ks < 8; ++ks)
            bk[ks] = *(const bf16x8*)(kbase + (size_t)(n0 + l16) * D + ks * 32 + quad * 8);
        #pragma unroll
        for (int ks = 0; ks < 8; ++ks)
            acc[nt] = __builtin_amdgcn_mfma_f32_16x16x32_bf16(aq[ks], bk[ks], acc[nt], 0, 0, 0);
    }

    // ---------- phase B: mask, exp (no max-sub: scores <= ~5), row-sum, normalize ----------
    // C-layout: row_local = quad*4 + reg, col = wave*256 + nt*16 + l16
    float rsum[4];
    #pragma unroll
    for (int r = 0; r < 4; ++r) rsum[r] = 0.f;

    {
        const int* mbase = maskg + ((size_t)b * S + i0 + quad * 4) * S;
        #pragma unroll
        for (int nt = 0; nt < 16; ++nt) {
            const int col = wave * 256 + nt * 16 + l16;
            #pragma unroll
            for (int r = 0; r < 4; ++r) {
                int m = __builtin_nontemporal_load(mbase + (size_t)r * S + col);
                float s = (m == 0) ? -1e9f : acc[nt][r] * SCALE;
                float e = __expf(s);            // exp(-1e9) underflows to 0 == reference
                acc[nt][r] = e;
                rsum[r] += e;
            }
        }
    }
    // reduce across the 16 lanes sharing a row (xor bits 0..3 stay in the quad-group)
    #pragma unroll
    for (int r = 0; r < 4; ++r) {
        float v = rsum[r];
        v += __shfl_xor(v, 1); v += __shfl_xor(v, 2);
        v += __shfl_xor(v, 4); v += __shfl_xor(v, 8);
        rsum[r] = v;
        if (l16 == 0) red[wave][quad * 4 + r] = v;
    }
    __syncthreads();

    float inv[4];
    #pragma unroll
    for (int r = 0; r < 4; ++r) {
        float tot = 0.f;
        #pragma unroll
        for (int w = 0; w < 8; ++w) tot += red[w][quad * 4 + r];
        inv[r] = 1.0f / tot;
    }

    // normalize, write attn (fp32, nontemporal), stash P (bf16) in LDS for phase C
    {
        float* abase = attng + ((size_t)b * S + i0 + quad * 4) * S;
        #pragma unroll
        for (int nt = 0; nt < 16; ++nt) {
            const int col = wave * 256 + nt * 16 + l16;
            #pragma unroll
            for (int r = 0; r < 4; ++r) {
                float p = acc[nt][r] * inv[r];
                __builtin_nontemporal_store(p, abase + (size_t)r * S + col);
                p_lds[quad * 4 + r][col] = f2bf(p);
            }
        }
    }
    __syncthreads();

    // ---------- phase C: out = P V (wave w owns dims [w*32, w*32+32)) ----------
    f32x4 oacc[2];
    #pragma unroll
    for (int nc = 0; nc < 2; ++nc) oacc[nc] = f32x4{0.f, 0.f, 0.f, 0.f};

    const short* vbase = vtb + (size_t)b * D * S;
    const int nb = wave * 32;
    for (int ks = 0; ks < 64; ++ks) {
        bf16x8 ap, bv[2];
        ap = *(const bf16x8*)&p_lds[l16][ks * 32 + quad * 8];
        #pragma unroll
        for (int nc = 0; nc < 2; ++nc)
            bv[nc] = *(const bf16x8*)(vbase + (size_t)(nb + nc * 16 + l16) * S + ks * 32 + quad * 8);
        #pragma unroll
        for (int nc = 0; nc < 2; ++nc)
            oacc[nc] = __builtin_amdgcn_mfma_f32_16x16x32_bf16(ap, bv[nc], oacc[nc], 0, 0, 0);
    }

    #pragma unroll
    for (int nc = 0; nc < 2; ++nc)
        #pragma unroll
        for (int r = 0; r < 4; ++r) {
            int row = i0 + quad * 4 + r;
            int col = nb + nc * 16 + l16;
            __builtin_nontemporal_store(oacc[nc][r], outg + ((size_t)b * S + row) * D + col);
        }
}

extern "C" void kernel_launch(void* const* d_in, const int* in_sizes, int n_in,
                              void* d_out, int out_size, void* d_ws, size_t ws_size,
                              hipStream_t stream) {
    const float* q    = (const float*)d_in[0];
    const float* k    = (const float*)d_in[1];
    const float* v    = (const float*)d_in[2];
    const int*   mask = (const int*)d_in[3];
    float* out  = (float*)d_out;
    float* attn = out + (size_t)B * S * D;     // tuple order: (out, attn)

    const size_t N = (size_t)B * S * D;        // 4,194,304 elements
    short* qb  = (short*)d_ws;                 // 8 MB
    short* kb  = qb + N;                       // 8 MB
    short* vtb = kb + N;                       // 8 MB (transposed V)

    const int n4 = (int)(N / 4);
    conv_bf16<<<dim3(n4 / 256), 256, 0, stream>>>(q, qb, n4);
    conv_bf16<<<dim3(n4 / 256), 256, 0, stream>>>(k, kb, n4);
    transpose_v<<<dim3(D / 64, S / 64, B), 256, 0, stream>>>(v, vtb);

    attn_mfma<<<dim3(S / TQ, B), 512, 0, stream>>>(qb, kb, vtb, mask, out, attn);
}

// Round 2
// 413.660 us; speedup vs baseline: 1.3060x; 1.3060x over previous
//
#include <hip/hip_runtime.h>

constexpr int B = 8, S = 2048, D = 256;
constexpr int TQ = 32;              // query rows per block (main kernel)
constexpr float SCALE = 0.0625f;    // 1/sqrt(256)
constexpr int PSTRIDE = 2056;       // 2048 + 8 bf16 pad -> 2-way bank aliasing (free)

typedef __attribute__((ext_vector_type(8))) short bf16x8;  // 8 bf16 in 4 VGPRs
typedef __attribute__((ext_vector_type(4))) float f32x4;

__device__ __forceinline__ short f2bf(float f) {
    union { float f; unsigned u; } c; c.f = f;
    unsigned u = c.u + 0x7fffu + ((c.u >> 16) & 1u);   // RNE
    return (short)(u >> 16);
}

// ---- pre-pass 1: fp32 -> bf16 elementwise (q, k) ----
__global__ void conv_bf16(const float* __restrict__ in, short* __restrict__ out, int n4) {
    int i = blockIdx.x * blockDim.x + threadIdx.x;
    if (i < n4) {
        float4 v = ((const float4*)in)[i];
        short4 o; o.x = f2bf(v.x); o.y = f2bf(v.y); o.z = f2bf(v.z); o.w = f2bf(v.w);
        ((short4*)out)[i] = o;
    }
}

// ---- pre-pass 2: V [B][S][D] fp32 -> V^T [B][D][S] bf16 ----
__global__ void transpose_v(const float* __restrict__ v, short* __restrict__ vt) {
    const int b = blockIdx.z;
    const int d0 = blockIdx.x * 64, k0 = blockIdx.y * 64;
    const int t = threadIdx.x;
    const int tr = t >> 4, tc = t & 15;
    __shared__ float tile[64][65];
    const float* vb = v + (size_t)b * S * D;
    #pragma unroll
    for (int r = 0; r < 4; ++r) {
        int key = r * 16 + tr;
        float4 x = *(const float4*)(vb + (size_t)(k0 + key) * D + d0 + tc * 4);
        tile[key][tc * 4 + 0] = x.x; tile[key][tc * 4 + 1] = x.y;
        tile[key][tc * 4 + 2] = x.z; tile[key][tc * 4 + 3] = x.w;
    }
    __syncthreads();
    short* vtb = vt + (size_t)b * D * S;
    #pragma unroll
    for (int r = 0; r < 4; ++r) {
        int d = r * 16 + tr;
        short4 o;
        o.x = f2bf(tile[tc * 4 + 0][d]); o.y = f2bf(tile[tc * 4 + 1][d]);
        o.z = f2bf(tile[tc * 4 + 2][d]); o.w = f2bf(tile[tc * 4 + 3][d]);
        *(short4*)(vtb + (size_t)(d0 + d) * S + k0 + tc * 4) = o;
    }
}

// ---- pre-pass 3: pack mask to bits matching the MFMA C-fragment layout ----
// pm[b][row][g][l16] (ushort), bit nt = (mask[b][row][g*256 + nt*16 + l16] != 0)
// One thread per output ushort: 16 coalesced 4B loads (64B per 16-lane chunk), 1 store.
__global__ void pack_mask(const int* __restrict__ mask, unsigned short* __restrict__ pm) {
    int t = blockIdx.x * blockDim.x + threadIdx.x;    // 0 .. B*S*128-1
    int l16 = t & 15;
    int g = (t >> 4) & 7;
    int rowlin = t >> 7;                              // b*S + row
    const int* mb = mask + (size_t)rowlin * S + g * 256 + l16;
    unsigned v = 0;
    #pragma unroll
    for (int nt = 0; nt < 16; ++nt)
        v |= (mb[(size_t)nt * 16] != 0 ? 1u : 0u) << nt;
    pm[t] = (unsigned short)v;
}

// ---- main fused kernel: 512 threads (8 waves), 1 block = 32 q-rows x 1 batch ----
// LDS: p_lds 32*2056*2 = 128.5 KB + red 1 KB -> 1 block/CU, 2 waves/SIMD
__global__ __launch_bounds__(512, 2) void attn_mfma(
    const short* __restrict__ qb, const short* __restrict__ kb,
    const short* __restrict__ vtb, const unsigned short* __restrict__ pmg,
    float* __restrict__ outg, float* __restrict__ attng)
{
    const int b = blockIdx.y;
    const int i0 = blockIdx.x * TQ;
    const int tid = threadIdx.x;
    const int wave = tid >> 6, lane = tid & 63;
    const int quad = lane >> 4, l16 = lane & 15;

    __shared__ short p_lds[TQ][PSTRIDE];
    __shared__ float red[8][TQ];

    // prefetch packed mask: one ushort per owned row (8 rows), consumed in phase B.
    // pm index: ((b*S + row)*8 + wave)*16 + l16 ; row = i0 + mt*16 + quad*4 + r
    unsigned pmv[2][4];
    {
        const unsigned short* pmb = pmg + (((size_t)b * S + i0 + quad * 4) * 8 + wave) * 16 + l16;
        #pragma unroll
        for (int mt = 0; mt < 2; ++mt)
            #pragma unroll
            for (int r = 0; r < 4; ++r)
                pmv[mt][r] = pmb[(size_t)(mt * 16 + r) * 128];
    }

    // ---------- phase A: scores = Q K^T (wave w owns keys [w*256, w*256+256)) ----------
    bf16x8 aq[2][8];
    const short* qbase = qb + ((size_t)b * S + i0) * D;
    #pragma unroll
    for (int mt = 0; mt < 2; ++mt)
        #pragma unroll
        for (int ks = 0; ks < 8; ++ks)
            aq[mt][ks] = *(const bf16x8*)(qbase + (size_t)(mt * 16 + l16) * D + ks * 32 + quad * 8);

    f32x4 acc[2][16];
    #pragma unroll
    for (int mt = 0; mt < 2; ++mt)
        #pragma unroll
        for (int nt = 0; nt < 16; ++nt)
            acc[mt][nt] = f32x4{0.f, 0.f, 0.f, 0.f};

    const short* kbase = kb + (size_t)b * S * D;
    #pragma unroll
    for (int nt = 0; nt < 16; ++nt) {
        const int n0 = wave * 256 + nt * 16;
        bf16x8 bk[8];
        #pragma unroll
        for (int ks = 0; ks < 8; ++ks)
            bk[ks] = *(const bf16x8*)(kbase + (size_t)(n0 + l16) * D + ks * 32 + quad * 8);
        #pragma unroll
        for (int ks = 0; ks < 8; ++ks) {
            acc[0][nt] = __builtin_amdgcn_mfma_f32_16x16x32_bf16(aq[0][ks], bk[ks], acc[0][nt], 0, 0, 0);
            acc[1][nt] = __builtin_amdgcn_mfma_f32_16x16x32_bf16(aq[1][ks], bk[ks], acc[1][nt], 0, 0, 0);
        }
    }

    // ---------- phase B: mask (from packed bits), exp, row-sum, normalize ----------
    // C-layout: row_local = mt*16 + quad*4 + r, col = wave*256 + nt*16 + l16
    float rsum[2][4];
    #pragma unroll
    for (int mt = 0; mt < 2; ++mt)
        #pragma unroll
        for (int r = 0; r < 4; ++r) rsum[mt][r] = 0.f;

    #pragma unroll
    for (int mt = 0; mt < 2; ++mt) {
        #pragma unroll
        for (int nt = 0; nt < 16; ++nt) {
            #pragma unroll
            for (int r = 0; r < 4; ++r) {
                float s = acc[mt][nt][r] * SCALE;
                float sv = ((pmv[mt][r] >> nt) & 1u) ? s : -1e9f;
                float e = __expf(sv);           // exp(-1e9) underflows to 0 == reference
                acc[mt][nt][r] = e;
                rsum[mt][r] += e;
            }
        }
    }
    // reduce across the 16 lanes sharing a row (xor bits 0..3 stay in the quad-group)
    #pragma unroll
    for (int mt = 0; mt < 2; ++mt)
        #pragma unroll
        for (int r = 0; r < 4; ++r) {
            float v = rsum[mt][r];
            v += __shfl_xor(v, 1); v += __shfl_xor(v, 2);
            v += __shfl_xor(v, 4); v += __shfl_xor(v, 8);
            rsum[mt][r] = v;
            if (l16 == 0) red[wave][mt * 16 + quad * 4 + r] = v;
        }
    __syncthreads();

    float inv[2][4];
    #pragma unroll
    for (int mt = 0; mt < 2; ++mt)
        #pragma unroll
        for (int r = 0; r < 4; ++r) {
            float tot = 0.f;
            #pragma unroll
            for (int w = 0; w < 8; ++w) tot += red[w][mt * 16 + quad * 4 + r];
            inv[mt][r] = 1.0f / tot;
        }

    // normalize, write attn (fp32), stash P (bf16) in LDS for phase C
    #pragma unroll
    for (int mt = 0; mt < 2; ++mt) {
        float* abase = attng + ((size_t)b * S + i0 + mt * 16 + quad * 4) * S;
        #pragma unroll
        for (int nt = 0; nt < 16; ++nt) {
            const int col = wave * 256 + nt * 16 + l16;
            #pragma unroll
            for (int r = 0; r < 4; ++r) {
                float p = acc[mt][nt][r] * inv[mt][r];
                abase[(size_t)r * S + col] = p;
                p_lds[mt * 16 + quad * 4 + r][col] = f2bf(p);
            }
        }
    }
    __syncthreads();

    // ---------- phase C: out = P V (wave w owns dims [w*32, w*32+32)) ----------
    f32x4 oacc[2][2];
    #pragma unroll
    for (int mt = 0; mt < 2; ++mt)
        #pragma unroll
        for (int nc = 0; nc < 2; ++nc) oacc[mt][nc] = f32x4{0.f, 0.f, 0.f, 0.f};

    const short* vbase = vtb + (size_t)b * D * S;
    const int nb = wave * 32;
    for (int ks = 0; ks < 64; ++ks) {
        bf16x8 ap[2], bv[2];
        #pragma unroll
        for (int mt = 0; mt < 2; ++mt)
            ap[mt] = *(const bf16x8*)&p_lds[mt * 16 + l16][ks * 32 + quad * 8];
        #pragma unroll
        for (int nc = 0; nc < 2; ++nc)
            bv[nc] = *(const bf16x8*)(vbase + (size_t)(nb + nc * 16 + l16) * S + ks * 32 + quad * 8);
        #pragma unroll
        for (int mt = 0; mt < 2; ++mt)
            #pragma unroll
            for (int nc = 0; nc < 2; ++nc)
                oacc[mt][nc] = __builtin_amdgcn_mfma_f32_16x16x32_bf16(ap[mt], bv[nc], oacc[mt][nc], 0, 0, 0);
    }

    #pragma unroll
    for (int mt = 0; mt < 2; ++mt)
        #pragma unroll
        for (int nc = 0; nc < 2; ++nc)
            #pragma unroll
            for (int r = 0; r < 4; ++r) {
                int row = i0 + mt * 16 + quad * 4 + r;
                int col = nb + nc * 16 + l16;
                outg[((size_t)b * S + row) * D + col] = oacc[mt][nc][r];
            }
}

extern "C" void kernel_launch(void* const* d_in, const int* in_sizes, int n_in,
                              void* d_out, int out_size, void* d_ws, size_t ws_size,
                              hipStream_t stream) {
    const float* q    = (const float*)d_in[0];
    const float* k    = (const float*)d_in[1];
    const float* v    = (const float*)d_in[2];
    const int*   mask = (const int*)d_in[3];
    float* out  = (float*)d_out;
    float* attn = out + (size_t)B * S * D;     // tuple order: (out, attn)

    const size_t N = (size_t)B * S * D;        // 4,194,304 elements
    short* qb  = (short*)d_ws;                 // 8 MB
    short* kb  = qb + N;                       // 8 MB
    short* vtb = kb + N;                       // 8 MB (transposed V)
    unsigned short* pm = (unsigned short*)(vtb + N);  // 4 MB packed mask

    const int n4 = (int)(N / 4);
    conv_bf16<<<dim3(n4 / 256), 256, 0, stream>>>(q, qb, n4);
    conv_bf16<<<dim3(n4 / 256), 256, 0, stream>>>(k, kb, n4);
    transpose_v<<<dim3(D / 64, S / 64, B), 256, 0, stream>>>(v, vtb);
    pack_mask<<<dim3((B * S * 128) / 256), 256, 0, stream>>>(mask, pm);

    attn_mfma<<<dim3(S / TQ, B), 512, 0, stream>>>(qb, kb, vtb, pm, out, attn);
}